// Round 7
// baseline (316.403 us; speedup 1.0000x reference)
//
#include <hip/hip_runtime.h>
#include <math.h>

#define NB_CLASSES 1024
#define SZ_EMBED 128
#define N_SAMPLES 262144
#define MTILE 64
#define CTILE 64
#define NBLOCKS (N_SAMPLES / MTILE)  // 4096
#define XSTRIDE 136  // bf16 elems; 272B row stride -> 2-way bank alias only (free per m136)

typedef __bf16 v8bf __attribute__((ext_vector_type(8)));
typedef float v4f __attribute__((ext_vector_type(4)));

// exp(+-32*cos + 3.2) = exp2(46.166...*(+-cos) + 4.6166...)
#define EXP_A 46.16624130844683f
#define EXP_B 4.616624130844683f

// shared-memory layout (bytes):
//   phase A:  xtile [0, 17408) | psum [17408, 18432) | dsum [18432, 19456) | tT [19456, 19712)
//   class loop: neg_lds [0, 4096) | pos_lds [4096, 8192)   <- ALIASES xtile on purpose:
//   overwriting xtile makes it unsound for the compiler to re-read A-fragments from LDS
//   inside the class loop (R5/R6: it kept VGPR=68 and re-read afrag every iter -> LDS wall).
#define SMEM_BYTES 19712

__device__ __forceinline__ unsigned short f2bf(float f) {
    union { float f; unsigned u; } v; v.f = f;
    unsigned u = v.u;
    unsigned rounding = 0x7FFFu + ((u >> 16) & 1u);
    return (unsigned short)((u + rounding) >> 16);
}
__device__ __forceinline__ float bfbits_lo(unsigned u) {
    union { unsigned u; float f; } v; v.u = u << 16; return v.f;
}
__device__ __forceinline__ float bfbits_hi(unsigned u) {
    union { unsigned u; float f; } v; v.u = u & 0xffff0000u; return v.f;
}

__global__ __launch_bounds__(256) void norm_proxies_kernel(
    const float* __restrict__ proxies, unsigned short* __restrict__ pn) {
    int wv = threadIdx.x >> 6;
    int lane = threadIdx.x & 63;
    int row = blockIdx.x * 4 + wv;  // grid = 256 -> rows 0..1023
    const float* src = proxies + (size_t)row * SZ_EMBED + lane * 2;
    float2 x = *(const float2*)src;
    float ss = x.x * x.x + x.y * x.y;
    #pragma unroll
    for (int off = 32; off; off >>= 1) ss += __shfl_xor(ss, off);
    float inv = rsqrtf(ss + 1e-12f);
    unsigned pk = (unsigned)f2bf(x.x * inv) | ((unsigned)f2bf(x.y * inv) << 16);
    *(unsigned*)(pn + (size_t)row * SZ_EMBED + lane * 2) = pk;
}

__global__ __launch_bounds__(256, 1) void main_kernel(
    const float* __restrict__ X, const int* __restrict__ T,
    const unsigned short* __restrict__ Pn,
    float* __restrict__ partial_neg, float* __restrict__ partial_pos) {
    __shared__ __align__(16) char smem[SMEM_BYTES];
    unsigned short* xtile = (unsigned short*)smem;
    float (*psum)[4] = (float(*)[4])(smem + 17408);
    float (*dsum)[4] = (float(*)[4])(smem + 18432);
    int* tT = (int*)(smem + 19456);
    float* neg_lds = (float*)smem;           // aliases xtile rows 0..15
    float* pos_lds = (float*)(smem + 4096);  // aliases xtile rows 15..30

    const int t = threadIdx.x;
    const int lane = t & 63;
    const int wv = t >> 6;
    const int quad = lane >> 4;
    const int l15 = lane & 15;
    const int sample_base = blockIdx.x * MTILE;

    // ---- phase A: load + normalize X tile into bf16 LDS; diag dot partials ----
    const int row = t >> 2, part = t & 3;  // 4 threads per sample row, 32 cols each
    {
        const float4* src = (const float4*)(X + (size_t)(sample_base + row) * SZ_EMBED + part * 32);
        float4 r[8];
        float ss = 0.f;
        #pragma unroll
        for (int j = 0; j < 8; ++j) {
            r[j] = src[j];
            ss += r[j].x * r[j].x + r[j].y * r[j].y + r[j].z * r[j].z + r[j].w * r[j].w;
        }
        psum[row][part] = ss;
        if (t < MTILE) tT[t] = T[sample_base + t];
        __syncthreads();
        float inv = rsqrtf(psum[row][0] + psum[row][1] + psum[row][2] + psum[row][3] + 1e-12f);
        unsigned short* dst = xtile + row * XSTRIDE + part * 32;
        #pragma unroll
        for (int j = 0; j < 8; ++j) {
            uint2 pk;
            pk.x = (unsigned)f2bf(r[j].x * inv) | ((unsigned)f2bf(r[j].y * inv) << 16);
            pk.y = (unsigned)f2bf(r[j].z * inv) | ((unsigned)f2bf(r[j].w * inv) << 16);
            *(uint2*)(dst + j * 4) = pk;
        }
        // diag partial: dot(X[row]*inv, Pn[T[row]]) over this thread's 32 cols
        int lbl = tT[row];
        const unsigned short* prow = Pn + (size_t)lbl * SZ_EMBED + part * 32;
        float d = 0.f;
        #pragma unroll
        for (int j = 0; j < 4; ++j) {  // 4 x uint4 = 4 x 8 bf16 = 32 cols
            uint4 pv = *(const uint4*)(prow + j * 8);
            float4 xa = r[2 * j], xb = r[2 * j + 1];
            d += bfbits_lo(pv.x) * xa.x + bfbits_hi(pv.x) * xa.y;
            d += bfbits_lo(pv.y) * xa.z + bfbits_hi(pv.y) * xa.w;
            d += bfbits_lo(pv.z) * xb.x + bfbits_hi(pv.z) * xb.y;
            d += bfbits_lo(pv.w) * xb.z + bfbits_hi(pv.w) * xb.w;
        }
        dsum[row][part] = d * inv;
    }
    __syncthreads();

    // ---- extract A fragments into registers (xtile is about to be clobbered) ----
    v8bf afrag[4][4];
    #pragma unroll
    for (int ri = 0; ri < 4; ++ri)
        #pragma unroll
        for (int kc = 0; kc < 4; ++kc)
            afrag[ri][kc] = *(const v8bf*)(xtile + (ri * 16 + l15) * XSTRIDE + kc * 32 + quad * 8);

    // ---- diag values into registers ----
    float diag_pos = 0.f, diag_neg = 0.f;
    int diag_lbl = 0;
    if (part == 0) {
        diag_lbl = tT[row];
        float dd = dsum[row][0] + dsum[row][1] + dsum[row][2] + dsum[row][3];
        diag_pos = __builtin_amdgcn_exp2f(fmaf(dd, -EXP_A, EXP_B));  // exp(-a(cos-mrg))
        diag_neg = __builtin_amdgcn_exp2f(fmaf(dd,  EXP_A, EXP_B));  // exp(+a(cos+mrg))
    }
    __syncthreads();  // everyone done reading xtile/dsum

    // ---- clobber xtile: zero the class accumulators ----
    *(float4*)(neg_lds + 4 * t) = float4{0.f, 0.f, 0.f, 0.f};
    *(float4*)(pos_lds + 4 * t) = float4{0.f, 0.f, 0.f, 0.f};
    __syncthreads();

    if (part == 0) {
        atomicAdd(&pos_lds[diag_lbl], diag_pos);
        atomicAdd(&neg_lds[diag_lbl], -diag_neg);  // cancel the unconditional neg term
    }

    // ---- class loop: B frags straight from global (Pn is L2-resident), no barriers ----
    const unsigned short* bptr = Pn + (size_t)(wv * 16 + l15) * SZ_EMBED + quad * 8;
    v8bf bfrag[2][4];
    #pragma unroll
    for (int kc = 0; kc < 4; ++kc)
        bfrag[0][kc] = *(const v8bf*)(bptr + kc * 32);

    #pragma unroll 2
    for (int ct = 0; ct < NB_CLASSES / CTILE; ++ct) {
        int cur = ct & 1;
        if (ct < NB_CLASSES / CTILE - 1) {
            const unsigned short* nb = bptr + (size_t)(ct + 1) * CTILE * SZ_EMBED;
            #pragma unroll
            for (int kc = 0; kc < 4; ++kc)
                bfrag[cur ^ 1][kc] = *(const v8bf*)(nb + kc * 32);
        }
        v4f zero = {0.f, 0.f, 0.f, 0.f};
        v4f acc[4] = {zero, zero, zero, zero};
        #pragma unroll
        for (int kc = 0; kc < 4; ++kc)
            #pragma unroll
            for (int ri = 0; ri < 4; ++ri)
                acc[ri] = __builtin_amdgcn_mfma_f32_16x16x32_bf16(afrag[ri][kc], bfrag[cur][kc], acc[ri], 0, 0, 0);

        // epilogue: exp2 per element, pairwise tree, one LDS atomic per lane
        float e[16];
        #pragma unroll
        for (int ri = 0; ri < 4; ++ri)
            #pragma unroll
            for (int r = 0; r < 4; ++r)
                e[ri * 4 + r] = __builtin_amdgcn_exp2f(fmaf(acc[ri][r], EXP_A, EXP_B));
        #pragma unroll
        for (int s = 8; s; s >>= 1)
            #pragma unroll
            for (int j = 0; j < s; ++j)
                e[j] += e[j + s];
        atomicAdd(&neg_lds[ct * CTILE + wv * 16 + l15], e[0]);
    }
    __syncthreads();

    // ---- write per-block partial rows: plain coalesced stores, no global atomics ----
    float* nrow = partial_neg + (size_t)blockIdx.x * NB_CLASSES;
    float* prow = partial_pos + (size_t)blockIdx.x * NB_CLASSES;
    *(float4*)(nrow + 4 * t) = *(const float4*)(neg_lds + 4 * t);
    *(float4*)(prow + 4 * t) = *(const float4*)(pos_lds + 4 * t);
}

// In-place tree reduce: block b sums rows [b*64, b*64+64) into row b*64.
// Reads fully coalesced (256 threads x float4 = one contiguous 4 KB row).
__global__ __launch_bounds__(256) void row_reduce_kernel(
    float* __restrict__ partial_neg, float* __restrict__ partial_pos) {
    const int t = threadIdx.x;
    const size_t base = (size_t)blockIdx.x * 64 * NB_CLASSES;
    float4 an = {0.f, 0.f, 0.f, 0.f}, ap = {0.f, 0.f, 0.f, 0.f};
    for (int r = 0; r < 64; ++r) {
        const float* nrow = partial_neg + base + (size_t)r * NB_CLASSES;
        const float* prow = partial_pos + base + (size_t)r * NB_CLASSES;
        float4 vn = *(const float4*)(nrow + 4 * t);
        float4 vp = *(const float4*)(prow + 4 * t);
        an.x += vn.x; an.y += vn.y; an.z += vn.z; an.w += vn.w;
        ap.x += vp.x; ap.y += vp.y; ap.z += vp.z; ap.w += vp.w;
    }
    *(float4*)(partial_neg + base + 4 * t) = an;
    *(float4*)(partial_pos + base + 4 * t) = ap;
}

__global__ __launch_bounds__(256) void finalize_kernel(
    const float* __restrict__ partial_neg, const float* __restrict__ partial_pos,
    float* __restrict__ out) {
    int t = threadIdx.x;
    // surviving rows after the reduce level: {0, 64, 128, ..., 4032}
    float4 ns = {0.f, 0.f, 0.f, 0.f}, ps = {0.f, 0.f, 0.f, 0.f};
    #pragma unroll 8
    for (int r = 0; r < 64; ++r) {
        float4 vn = *(const float4*)(partial_neg + (size_t)r * 64 * NB_CLASSES + 4 * t);
        float4 vp = *(const float4*)(partial_pos + (size_t)r * 64 * NB_CLASSES + 4 * t);
        ns.x += vn.x; ns.y += vn.y; ns.z += vn.z; ns.w += vn.w;
        ps.x += vp.x; ps.y += vp.y; ps.z += vp.z; ps.w += vp.w;
    }
    float lp_pos = log1pf(ps.x) + log1pf(ps.y) + log1pf(ps.z) + log1pf(ps.w);
    float lp_neg = log1pf(ns.x) + log1pf(ns.y) + log1pf(ns.z) + log1pf(ns.w);
    float valid = (ps.x != 0.f) + (ps.y != 0.f) + (ps.z != 0.f) + (ps.w != 0.f);
    #pragma unroll
    for (int off = 32; off; off >>= 1) {
        lp_pos += __shfl_xor(lp_pos, off);
        lp_neg += __shfl_xor(lp_neg, off);
        valid  += __shfl_xor(valid, off);
    }
    __shared__ float s[3][4];
    int wv = t >> 6, lane = t & 63;
    if (lane == 0) { s[0][wv] = lp_pos; s[1][wv] = lp_neg; s[2][wv] = valid; }
    __syncthreads();
    if (t == 0) {
        float P = s[0][0] + s[0][1] + s[0][2] + s[0][3];
        float Ng = s[1][0] + s[1][1] + s[1][2] + s[1][3];
        float V = s[2][0] + s[2][1] + s[2][2] + s[2][3];
        float pos_term = (V > 0.f) ? (P / fmaxf(V, 1.f)) : 0.f;
        float neg_term = Ng / (float)NB_CLASSES;
        out[0] = pos_term + neg_term;
        out[1] = pos_term;
        out[2] = neg_term;
    }
}

extern "C" void kernel_launch(void* const* d_in, const int* in_sizes, int n_in,
                              void* d_out, int out_size, void* d_ws, size_t ws_size,
                              hipStream_t stream) {
    const float* X = (const float*)d_in[0];
    const float* proxies = (const float*)d_in[1];
    const int* T = (const int*)d_in[2];
    float* out = (float*)d_out;

    // ws layout: Pn (256 KB) | partial_neg (16 MB) | partial_pos (16 MB)
    char* ws = (char*)d_ws;
    unsigned short* Pn = (unsigned short*)ws;
    float* partial_neg = (float*)(ws + (size_t)NB_CLASSES * SZ_EMBED * sizeof(unsigned short));
    float* partial_pos = partial_neg + (size_t)NBLOCKS * NB_CLASSES;

    norm_proxies_kernel<<<NB_CLASSES / 4, 256, 0, stream>>>(proxies, Pn);
    main_kernel<<<NBLOCKS, 256, 0, stream>>>(X, T, Pn, partial_neg, partial_pos);
    row_reduce_kernel<<<64, 256, 0, stream>>>(partial_neg, partial_pos);
    finalize_kernel<<<1, 256, 0, stream>>>(partial_neg, partial_pos, out);
}

// Round 8
// 311.694 us; speedup vs baseline: 1.0151x; 1.0151x over previous
//
#include <hip/hip_runtime.h>
#include <math.h>

#define NB_CLASSES 1024
#define SZ_EMBED 128
#define N_SAMPLES 262144
#define MTILE 64
#define CTILE 64
#define NBLOCKS (N_SAMPLES / MTILE)  // 4096
#define XSTRIDE 136  // bf16 elems; 272B row stride -> 2-way bank alias only (free per m136)

typedef __bf16 v8bf __attribute__((ext_vector_type(8)));
typedef float v4f __attribute__((ext_vector_type(4)));

// exp(+-32*cos + 3.2) = exp2(46.166...*(+-cos) + 4.6166...)
#define EXP_A 46.16624130844683f
#define EXP_B 4.616624130844683f

// R7 post-mortem: VGPR_Count=68 is arch-VGPRs only; afrag/acc live in AGPRs
// (unified file) -> true footprint ~164 regs -> 129-256 bracket -> ~8-10
// waves/CU (Occupancy 31%). Kernel is occupancy-starved on latency, not
// pipe-bound. R8: force total <=128 regs via __launch_bounds__(256,4)
// (4 waves/SIMD min => <=128 regs/wave) and single-buffer bfrag so the
// demand (~112) fits without scratch spill.
#define SMEM_BYTES 19712

__device__ __forceinline__ unsigned short f2bf(float f) {
    union { float f; unsigned u; } v; v.f = f;
    unsigned u = v.u;
    unsigned rounding = 0x7FFFu + ((u >> 16) & 1u);
    return (unsigned short)((u + rounding) >> 16);
}
__device__ __forceinline__ float bfbits_lo(unsigned u) {
    union { unsigned u; float f; } v; v.u = u << 16; return v.f;
}
__device__ __forceinline__ float bfbits_hi(unsigned u) {
    union { unsigned u; float f; } v; v.u = u & 0xffff0000u; return v.f;
}

__global__ __launch_bounds__(256) void norm_proxies_kernel(
    const float* __restrict__ proxies, unsigned short* __restrict__ pn) {
    int wv = threadIdx.x >> 6;
    int lane = threadIdx.x & 63;
    int row = blockIdx.x * 4 + wv;  // grid = 256 -> rows 0..1023
    const float* src = proxies + (size_t)row * SZ_EMBED + lane * 2;
    float2 x = *(const float2*)src;
    float ss = x.x * x.x + x.y * x.y;
    #pragma unroll
    for (int off = 32; off; off >>= 1) ss += __shfl_xor(ss, off);
    float inv = rsqrtf(ss + 1e-12f);
    unsigned pk = (unsigned)f2bf(x.x * inv) | ((unsigned)f2bf(x.y * inv) << 16);
    *(unsigned*)(pn + (size_t)row * SZ_EMBED + lane * 2) = pk;
}

__global__ __launch_bounds__(256, 4) void main_kernel(
    const float* __restrict__ X, const int* __restrict__ T,
    const unsigned short* __restrict__ Pn,
    float* __restrict__ partial_neg, float* __restrict__ partial_pos) {
    __shared__ __align__(16) char smem[SMEM_BYTES];
    unsigned short* xtile = (unsigned short*)smem;
    float (*psum)[4] = (float(*)[4])(smem + 17408);
    float (*dsum)[4] = (float(*)[4])(smem + 18432);
    int* tT = (int*)(smem + 19456);
    float* neg_lds = (float*)smem;           // aliases xtile (clobbered after afrag extract)
    float* pos_lds = (float*)(smem + 4096);

    const int t = threadIdx.x;
    const int lane = t & 63;
    const int wv = t >> 6;
    const int quad = lane >> 4;
    const int l15 = lane & 15;
    const int sample_base = blockIdx.x * MTILE;

    // ---- phase A: load + normalize X tile into bf16 LDS; diag dot partials ----
    const int row = t >> 2, part = t & 3;  // 4 threads per sample row, 32 cols each
    {
        const float4* src = (const float4*)(X + (size_t)(sample_base + row) * SZ_EMBED + part * 32);
        float4 r[8];
        float ss = 0.f;
        #pragma unroll
        for (int j = 0; j < 8; ++j) {
            r[j] = src[j];
            ss += r[j].x * r[j].x + r[j].y * r[j].y + r[j].z * r[j].z + r[j].w * r[j].w;
        }
        psum[row][part] = ss;
        if (t < MTILE) tT[t] = T[sample_base + t];
        __syncthreads();
        float inv = rsqrtf(psum[row][0] + psum[row][1] + psum[row][2] + psum[row][3] + 1e-12f);
        unsigned short* dst = xtile + row * XSTRIDE + part * 32;
        #pragma unroll
        for (int j = 0; j < 8; ++j) {
            uint2 pk;
            pk.x = (unsigned)f2bf(r[j].x * inv) | ((unsigned)f2bf(r[j].y * inv) << 16);
            pk.y = (unsigned)f2bf(r[j].z * inv) | ((unsigned)f2bf(r[j].w * inv) << 16);
            *(uint2*)(dst + j * 4) = pk;
        }
        // diag partial: dot(X[row]*inv, Pn[T[row]]) over this thread's 32 cols
        int lbl = tT[row];
        const unsigned short* prow = Pn + (size_t)lbl * SZ_EMBED + part * 32;
        float d = 0.f;
        #pragma unroll
        for (int j = 0; j < 4; ++j) {  // 4 x uint4 = 4 x 8 bf16 = 32 cols
            uint4 pv = *(const uint4*)(prow + j * 8);
            float4 xa = r[2 * j], xb = r[2 * j + 1];
            d += bfbits_lo(pv.x) * xa.x + bfbits_hi(pv.x) * xa.y;
            d += bfbits_lo(pv.y) * xa.z + bfbits_hi(pv.y) * xa.w;
            d += bfbits_lo(pv.z) * xb.x + bfbits_hi(pv.z) * xb.y;
            d += bfbits_lo(pv.w) * xb.z + bfbits_hi(pv.w) * xb.w;
        }
        dsum[row][part] = d * inv;
    }
    __syncthreads();

    // ---- extract A fragments into registers (xtile is about to be clobbered) ----
    v8bf afrag[4][4];
    #pragma unroll
    for (int ri = 0; ri < 4; ++ri)
        #pragma unroll
        for (int kc = 0; kc < 4; ++kc)
            afrag[ri][kc] = *(const v8bf*)(xtile + (ri * 16 + l15) * XSTRIDE + kc * 32 + quad * 8);

    // ---- diag values into registers ----
    float diag_pos = 0.f, diag_neg = 0.f;
    int diag_lbl = 0;
    if (part == 0) {
        diag_lbl = tT[row];
        float dd = dsum[row][0] + dsum[row][1] + dsum[row][2] + dsum[row][3];
        diag_pos = __builtin_amdgcn_exp2f(fmaf(dd, -EXP_A, EXP_B));  // exp(-a(cos-mrg))
        diag_neg = __builtin_amdgcn_exp2f(fmaf(dd,  EXP_A, EXP_B));  // exp(+a(cos+mrg))
    }
    __syncthreads();  // everyone done reading xtile/dsum

    // ---- clobber xtile: zero the class accumulators ----
    *(float4*)(neg_lds + 4 * t) = float4{0.f, 0.f, 0.f, 0.f};
    *(float4*)(pos_lds + 4 * t) = float4{0.f, 0.f, 0.f, 0.f};
    __syncthreads();

    if (part == 0) {
        atomicAdd(&pos_lds[diag_lbl], diag_pos);
        atomicAdd(&neg_lds[diag_lbl], -diag_neg);  // cancel the unconditional neg term
    }

    // ---- class loop: single-buffered B frags from global (Pn is L2-resident).
    // Pipeline per iter: MFMA(consume bfrag) -> issue next 4 loads -> epilogue
    // (exp2 tree + ds_add, ~200+ cyc) overlaps the load latency.
    const unsigned short* bptr = Pn + (size_t)(wv * 16 + l15) * SZ_EMBED + quad * 8;
    v8bf bfrag[4];
    #pragma unroll
    for (int kc = 0; kc < 4; ++kc)
        bfrag[kc] = *(const v8bf*)(bptr + kc * 32);

    for (int ct = 0; ct < NB_CLASSES / CTILE; ++ct) {
        v4f zero = {0.f, 0.f, 0.f, 0.f};
        v4f acc[4] = {zero, zero, zero, zero};
        #pragma unroll
        for (int kc = 0; kc < 4; ++kc)
            #pragma unroll
            for (int ri = 0; ri < 4; ++ri)
                acc[ri] = __builtin_amdgcn_mfma_f32_16x16x32_bf16(afrag[ri][kc], bfrag[kc], acc[ri], 0, 0, 0);

        // issue next tile's loads (overwrites bfrag; MFMAs above already read it)
        if (ct < NB_CLASSES / CTILE - 1) {
            const unsigned short* nb = bptr + (size_t)(ct + 1) * CTILE * SZ_EMBED;
            #pragma unroll
            for (int kc = 0; kc < 4; ++kc)
                bfrag[kc] = *(const v8bf*)(nb + kc * 32);
        }

        // epilogue: exp2 per element, pairwise tree, one LDS atomic per lane
        float e[16];
        #pragma unroll
        for (int ri = 0; ri < 4; ++ri)
            #pragma unroll
            for (int r = 0; r < 4; ++r)
                e[ri * 4 + r] = __builtin_amdgcn_exp2f(fmaf(acc[ri][r], EXP_A, EXP_B));
        #pragma unroll
        for (int s = 8; s; s >>= 1)
            #pragma unroll
            for (int j = 0; j < s; ++j)
                e[j] += e[j + s];
        atomicAdd(&neg_lds[ct * CTILE + wv * 16 + l15], e[0]);
    }
    __syncthreads();

    // ---- write per-block partial rows: plain coalesced stores, no global atomics ----
    float* nrow = partial_neg + (size_t)blockIdx.x * NB_CLASSES;
    float* prow = partial_pos + (size_t)blockIdx.x * NB_CLASSES;
    *(float4*)(nrow + 4 * t) = *(const float4*)(neg_lds + 4 * t);
    *(float4*)(prow + 4 * t) = *(const float4*)(pos_lds + 4 * t);
}

// In-place tree reduce: block b sums rows [b*64, b*64+64) into row b*64.
// Reads fully coalesced (256 threads x float4 = one contiguous 4 KB row).
__global__ __launch_bounds__(256) void row_reduce_kernel(
    float* __restrict__ partial_neg, float* __restrict__ partial_pos) {
    const int t = threadIdx.x;
    const size_t base = (size_t)blockIdx.x * 64 * NB_CLASSES;
    float4 an = {0.f, 0.f, 0.f, 0.f}, ap = {0.f, 0.f, 0.f, 0.f};
    for (int r = 0; r < 64; ++r) {
        const float* nrow = partial_neg + base + (size_t)r * NB_CLASSES;
        const float* prow = partial_pos + base + (size_t)r * NB_CLASSES;
        float4 vn = *(const float4*)(nrow + 4 * t);
        float4 vp = *(const float4*)(prow + 4 * t);
        an.x += vn.x; an.y += vn.y; an.z += vn.z; an.w += vn.w;
        ap.x += vp.x; ap.y += vp.y; ap.z += vp.z; ap.w += vp.w;
    }
    *(float4*)(partial_neg + base + 4 * t) = an;
    *(float4*)(partial_pos + base + 4 * t) = ap;
}

__global__ __launch_bounds__(256) void finalize_kernel(
    const float* __restrict__ partial_neg, const float* __restrict__ partial_pos,
    float* __restrict__ out) {
    int t = threadIdx.x;
    // surviving rows after the reduce level: {0, 64, 128, ..., 4032}
    float4 ns = {0.f, 0.f, 0.f, 0.f}, ps = {0.f, 0.f, 0.f, 0.f};
    #pragma unroll 8
    for (int r = 0; r < 64; ++r) {
        float4 vn = *(const float4*)(partial_neg + (size_t)r * 64 * NB_CLASSES + 4 * t);
        float4 vp = *(const float4*)(partial_pos + (size_t)r * 64 * NB_CLASSES + 4 * t);
        ns.x += vn.x; ns.y += vn.y; ns.z += vn.z; ns.w += vn.w;
        ps.x += vp.x; ps.y += vp.y; ps.z += vp.z; ps.w += vp.w;
    }
    float lp_pos = log1pf(ps.x) + log1pf(ps.y) + log1pf(ps.z) + log1pf(ps.w);
    float lp_neg = log1pf(ns.x) + log1pf(ns.y) + log1pf(ns.z) + log1pf(ns.w);
    float valid = (ps.x != 0.f) + (ps.y != 0.f) + (ps.z != 0.f) + (ps.w != 0.f);
    #pragma unroll
    for (int off = 32; off; off >>= 1) {
        lp_pos += __shfl_xor(lp_pos, off);
        lp_neg += __shfl_xor(lp_neg, off);
        valid  += __shfl_xor(valid, off);
    }
    __shared__ float s[3][4];
    int wv = t >> 6, lane = t & 63;
    if (lane == 0) { s[0][wv] = lp_pos; s[1][wv] = lp_neg; s[2][wv] = valid; }
    __syncthreads();
    if (t == 0) {
        float P = s[0][0] + s[0][1] + s[0][2] + s[0][3];
        float Ng = s[1][0] + s[1][1] + s[1][2] + s[1][3];
        float V = s[2][0] + s[2][1] + s[2][2] + s[2][3];
        float pos_term = (V > 0.f) ? (P / fmaxf(V, 1.f)) : 0.f;
        float neg_term = Ng / (float)NB_CLASSES;
        out[0] = pos_term + neg_term;
        out[1] = pos_term;
        out[2] = neg_term;
    }
}

extern "C" void kernel_launch(void* const* d_in, const int* in_sizes, int n_in,
                              void* d_out, int out_size, void* d_ws, size_t ws_size,
                              hipStream_t stream) {
    const float* X = (const float*)d_in[0];
    const float* proxies = (const float*)d_in[1];
    const int* T = (const int*)d_in[2];
    float* out = (float*)d_out;

    // ws layout: Pn (256 KB) | partial_neg (16 MB) | partial_pos (16 MB)
    char* ws = (char*)d_ws;
    unsigned short* Pn = (unsigned short*)ws;
    float* partial_neg = (float*)(ws + (size_t)NB_CLASSES * SZ_EMBED * sizeof(unsigned short));
    float* partial_pos = partial_neg + (size_t)NBLOCKS * NB_CLASSES;

    norm_proxies_kernel<<<NB_CLASSES / 4, 256, 0, stream>>>(proxies, Pn);
    main_kernel<<<NBLOCKS, 256, 0, stream>>>(X, T, Pn, partial_neg, partial_pos);
    row_reduce_kernel<<<64, 256, 0, stream>>>(partial_neg, partial_pos);
    finalize_kernel<<<1, 256, 0, stream>>>(partial_neg, partial_pos, out);
}